// Round 16
// baseline (53.621 us; speedup 1.0000x reference)
//
#include <hip/hip_runtime.h>
#include <hip/hip_bf16.h>

#define BATCH 64
#define NGT 16
#define NSTAT 192
#define NBUK 256
#define NCHUNK 50
#define INV_IMG (1.0f/224.0f)
#define L2E 1.442695040888963f
#define LN2 0.693147180559945f
#define MASK21 ((1u<<21)-1u)

typedef float f32x2 __attribute__((ext_vector_type(2)));

__device__ __forceinline__ f32x2 v2max(f32x2 a, f32x2 b) { return __builtin_elementwise_max(a, b); }
__device__ __forceinline__ f32x2 v2min(f32x2 a, f32x2 b) { return __builtin_elementwise_min(a, b); }
__device__ __forceinline__ f32x2 v2fma(f32x2 a, f32x2 b, f32x2 c) { return __builtin_elementwise_fma(a, b, c); }

__device__ __forceinline__ float wredf(float v) {
  #pragma unroll
  for (int o = 32; o > 0; o >>= 1) v += __shfl_down(v, o, 64);
  return v;
}
__device__ __forceinline__ float softplus_neg(float ax) {
  // log1p(exp(-ax)) for ax >= 0 via HW exp2/log2
  float e = __builtin_amdgcn_exp2f(-ax * L2E);
  return __builtin_amdgcn_logf(1.0f + e) * LN2;
}

// Per-anchor kernel (R11 base): 4 anchors/thread within one row. Analytic
// anchors, y-hoist + block-uniform GT mask + wave ballot skip. Hot loop now
// tracks only threshold maxima posM/negM (packed fma+max, no argmax chain);
// argmax bj is recomputed in the deferred positive phase.
// Negatives -> per-WAVE u32 LDS hist (cnt<<21 | sum*2^8).
// Positives -> tiny LDS queue; processed post-barrier by wave 0 lane-parallel.
// grid = (50 chunks, BATCH).
__global__ __launch_bounds__(256, 6)
void score_kernel(const float* __restrict__ p0, const float* __restrict__ p1,
                  const float* __restrict__ p2,
                  const float* __restrict__ tboxes, const int* __restrict__ tlabels,
                  unsigned* __restrict__ slabG,
                  float4* __restrict__ statG, float* __restrict__ out)
{
  const int c = blockIdx.x, b = blockIdx.y;
  const int tid = threadIdx.x;
  const int wv = tid >> 6;

  int s, ch, row, x0, W, HH; float st, sh; const float* pred; bool valid;
  if (c < 37) {
    int seg = c*256 + tid; valid = seg < 9408;
    if (!valid) seg = 0;
    ch = seg / 3136; int rem = seg - ch*3136; row = rem / 28; x0 = (rem - row*28)*4;
    s=0; W=112; HH=12544; st=2.f; sh=8.f+4.f*(float)ch; pred=p0;
  } else if (c < 47) {
    int seg = (c-37)*256 + tid; valid = seg < 2352;
    if (!valid) seg = 0;
    ch = seg / 784; int rem = seg - ch*784; row = rem / 14; x0 = (rem - row*14)*4;
    s=1; W=56; HH=3136; st=4.f; sh=24.f+8.f*(float)ch; pred=p1;
  } else {
    int seg = (c-47)*256 + tid; valid = seg < 588;
    if (!valid) seg = 0;
    ch = seg / 196; int rem = seg - ch*196; row = rem / 7; x0 = (rem - row*7)*4;
    s=2; W=28; HH=784; st=8.f; sh=48.f+16.f*(float)ch; pred=p2;
  }

  __shared__ float sbx1[NGT], sby1[NGT], sbx2[NGT], sby2[NGT], sab[NGT];
  __shared__ unsigned hist[4*NBUK];    // per-wave private, u32 packed
  __shared__ int sqcnt;
  __shared__ unsigned squeue[1024];
  __shared__ unsigned smask;

  #pragma unroll
  for (int j = 0; j < 4; ++j) hist[tid + 256*j] = 0u;
  if (tid == 0) sqcnt = 0;
  bool keep = false;
  if (tid < NGT) {
    float x1 = tboxes[(b*NGT + tid)*4 + 0] * INV_IMG;
    float y1 = tboxes[(b*NGT + tid)*4 + 1] * INV_IMG;
    float x2 = tboxes[(b*NGT + tid)*4 + 2] * INV_IMG;
    float y2 = tboxes[(b*NGT + tid)*4 + 3] * INV_IMG;
    sbx1[tid]=x1; sby1[tid]=y1; sbx2[tid]=x2; sby2[tid]=y2;
    sab[tid] = (x2-x1)*(y2-y1);
    // block y-band (uniform): rows of segLo..segHi, conservative max half-size
    int base, lim, per, wseg;
    if (s == 0)      { base = c*256;      lim = 9408; per = 3136; wseg = 28; }
    else if (s == 1) { base = (c-37)*256; lim = 2352; per = 784;  wseg = 14; }
    else             { base = (c-47)*256; lim = 588;  per = 196;  wseg = 7;  }
    int segLo = base, segHi = min(base + 255, lim - 1);
    int chLo = segLo / per, chHi = segHi / per;
    int rLo = (segLo - chLo*per) / wseg, rHi = (segHi - chHi*per) / wseg;
    if (chLo != chHi) { rLo = 0; rHi = W - 1; }
    float shm = (s==0) ? 16.f : ((s==1) ? 40.f : 80.f);
    float by1 = (((float)rLo + 0.5f)*st - shm) * INV_IMG;
    float by2 = (((float)rHi + 0.5f)*st + shm) * INV_IMG;
    keep = (y2 >= by1) && (y1 <= by2);
  }
  unsigned mk = (unsigned)(__ballot(keep) & 0xFFFFULL);
  if (tid == 0) smask = mk;
  __syncthreads();
  const unsigned mask = smask;

  // analytic anchors (bit-identical to reference values)
  const float fy  = ((float)row + 0.5f)*st;
  const float ay1 = (fy - sh)*INV_IMG;
  const float ay2 = (fy + sh)*INV_IMG;
  const float A0  = ((float)x0 + 0.5f)*st - sh;
  const float hA  = ay2 - ay1;
  f32x2 ax1a, ax1b, ax2a, ax2b;
  {
    float f0 = A0, f1 = A0 + st, f2 = A0 + st*2.f, f3 = A0 + st*3.f;
    ax1a = (f32x2){f0*INV_IMG, f1*INV_IMG};
    ax1b = (f32x2){f2*INV_IMG, f3*INV_IMG};
    ax2a = (f32x2){(f0+2.f*sh)*INV_IMG, (f1+2.f*sh)*INV_IMG};
    ax2b = (f32x2){(f2+2.f*sh)*INV_IMG, (f3+2.f*sh)*INV_IMG};
  }
  const f32x2 hAv = (f32x2){hA, hA};
  const f32x2 arA = (ax2a - ax1a) * hAv;
  const f32x2 arB = (ax2b - ax1b) * hAv;
  // threshold maxima: posM = max_j(inter - 0.5*den), negM = max_j(inter - 0.4*den)
  f32x2 posA = (f32x2){-1.f,-1.f}, posB = (f32x2){-1.f,-1.f};
  f32x2 negA = (f32x2){-1.f,-1.f}, negB = (f32x2){-1.f,-1.f};
  const f32x2 mhalf = (f32x2){-0.5f,-0.5f};
  const f32x2 mp4   = (f32x2){-0.4f,-0.4f};

  const int hw0 = row*W + x0;
  const float* pb = pred + ((size_t)b*24 + (size_t)ch*8) * (size_t)HH;
  float4 o0 = make_float4(0.f,0.f,0.f,0.f);
  if (valid) o0 = *reinterpret_cast<const float4*>(pb + 4*HH + hw0);
  float obj[4] = {o0.x,o0.y,o0.z,o0.w};

  const f32x2 zero2 = (f32x2){0.f, 0.f};
  const f32x2 eps2  = (f32x2){1e-9f, 1e-9f};
  #pragma unroll
  for (int j = 0; j < NGT; ++j) {
    if (!(mask & (1u << j))) continue;          // block-uniform cheap skip
    float ly = fmaxf(ay1, sby1[j]);
    float ry = fminf(ay2, sby2[j]);
    float hy = ry - ly;
    if (__ballot(hy > 0.f)) {
      float h = fmaxf(hy, 0.f);
      float bx1 = sbx1[j], bx2 = sbx2[j], ab = sab[j];
      const f32x2 hv  = (f32x2){h, h};
      const f32x2 b1v = (f32x2){bx1, bx1};
      const f32x2 b2v = (f32x2){bx2, bx2};
      const f32x2 abv = (f32x2){ab, ab};
      // pair A (q=0,1): identical FP order for inter/den; threshold via exact
      // fma-sign (skipped boxes only ever contribute negatives -> skip-safe)
      f32x2 wA = v2max(v2min(ax2a, b2v) - v2max(ax1a, b1v), zero2);
      f32x2 iA = wA * hv;
      f32x2 dA = (arA + abv) - iA + eps2;
      posA = v2max(posA, v2fma(mhalf, dA, iA));
      negA = v2max(negA, v2fma(mp4,   dA, iA));
      // pair B (q=2,3)
      f32x2 wB = v2max(v2min(ax2b, b2v) - v2max(ax1b, b1v), zero2);
      f32x2 iB = wB * hv;
      f32x2 dB = (arB + abv) - iB + eps2;
      posB = v2max(posB, v2fma(mhalf, dB, iB));
      negB = v2max(negB, v2fma(mp4,   dB, iB));
    }
  }

  const float posQ[4] = {posA.x, posA.y, posB.x, posB.y};
  const float negQ[4] = {negA.x, negA.y, negB.x, negB.y};

  unsigned* myhist = hist + wv*NBUK;
  #pragma unroll
  for (int q = 0; q < 4; ++q) {
    bool pos = valid && (posQ[q] >= 0.f);   // iou >= 0.5
    bool neg = valid && (negQ[q] <  0.f);   // iou <  0.4
    if (neg) {
      float x = obj[q];
      float bce = fmaxf(x, 0.f) + softplus_neg(fabsf(x));
      int bk = min(NBUK-1, (int)(bce * 32.f));
      unsigned pk = (1u << 21) | (unsigned)(bce * 256.f + 0.5f);
      atomicAdd(&myhist[bk], pk);
    }
    if (pos) {     // rare: defer everything (incl. argmax) to wave-0 phase
      int qi = atomicAdd(&sqcnt, 1);
      squeue[qi] = ((unsigned)ch<<14) | ((unsigned)row<<7) | (unsigned)(x0 + q);
    }
  }
  __syncthreads();

  // wave 0: process queued positives lane-parallel (loads overlap across lanes)
  if (tid < 64) {
    const int n = sqcnt;
    float anp = 0.f, avb = 0.f, avc = 0.f, avl = 0.f;
    for (int base = 0; base < n; base += 64) {
      int i = base + tid;
      float cf = 0.f, bce = 0.f, ce = 0.f, ssum = 0.f;
      if (i < n) {
        unsigned rec = squeue[i];
        int x   = rec & 127;
        int rw  = (rec >> 7) & 127;
        int ch2 = (rec >> 14) & 3;
        float sh2 = (s==0) ? 8.f+4.f*(float)ch2
                  : (s==1) ? 24.f+8.f*(float)ch2 : 48.f+16.f*(float)ch2;
        const float* pbq = pred + ((size_t)b*24 + (size_t)ch2*8) * (size_t)HH;
        const int hw = rw*W + x;
        // anchor (bit-identical analytic form)
        float fyq = ((float)rw + 0.5f)*st;
        float qay1 = (fyq - sh2)*INV_IMG, qay2 = (fyq + sh2)*INV_IMG;
        float fx = ((float)x + 0.5f)*st - sh2;
        float qax1 = fx*INV_IMG, qax2 = (fx + 2.f*sh2)*INV_IMG;
        float areaA = (qax2-qax1)*(qay2-qay1);

        // recompute argmax bj over ALL 16 boxes (cross-mult, first-max kept;
        // decision-identical to the R11 hot-loop chain)
        float bIx = -1.f, bDx = 1.f; int j = 0;
        #pragma unroll
        for (int jj = 0; jj < NGT; ++jj) {
          float lx = fmaxf(qax1, sbx1[jj]);
          float ly2 = fmaxf(qay1, sby1[jj]);
          float rx = fminf(qax2, sbx2[jj]);
          float ry2 = fminf(qay2, sby2[jj]);
          float w2 = fmaxf(rx-lx, 0.f), h2 = fmaxf(ry2-ly2, 0.f);
          float inter = w2*h2;
          float den = (areaA + sab[jj]) - inter + 1e-9f;
          if (inter*bDx > bIx*den) { bIx = inter; bDx = den; j = jj; }
        }

        float xo = pbq[4*HH + hw];
        bce = fmaxf(xo, 0.f) - xo + softplus_neg(fabsf(xo));

        float c0 = pbq[5*HH + hw], c1 = pbq[6*HH + hw], c2 = pbq[7*HH + hw];
        float m = fmaxf(c0, fmaxf(c1, c2));
        float e0 = __builtin_amdgcn_exp2f((c0-m)*L2E);
        float e1 = __builtin_amdgcn_exp2f((c1-m)*L2E);
        float e2 = __builtin_amdgcn_exp2f((c2-m)*L2E);
        float lse = m + __builtin_amdgcn_logf(e0+e1+e2) * LN2;
        int lab = tlabels[b*NGT + j] - 1;
        float cl = (lab==0)?c0:((lab==1)?c1:c2);
        ce = lse - cl;

        float bx1=sbx1[j], by1=sby1[j], bx2=sbx2[j], by2=sby2[j];
        float gcx = 0.5f*(bx1+bx2), gcy = 0.5f*(by1+by2);
        float gw = bx2-bx1, gh = by2-by1;
        float acx = 0.5f*(qax1+qax2), acy = 0.5f*(qay1+qay2);
        float aw = qax2-qax1, ah = qay2-qay1;
        float t0 = (gcx-acx)/aw;
        float t1 = (gcy-acy)/ah;
        float t2 = __builtin_amdgcn_logf(gw/aw + 1e-6f) * LN2;
        float t3 = __builtin_amdgcn_logf(gh/ah + 1e-6f) * LN2;
        float bp0 = pbq[0*HH+hw], bp1 = pbq[1*HH+hw];
        float bp2 = pbq[2*HH+hw], bp3 = pbq[3*HH+hw];
        float d, ad;
        d = bp0-t0; ad = fabsf(d); ssum += (ad<1.f)? 0.5f*d*d : ad-0.5f;
        d = bp1-t1; ad = fabsf(d); ssum += (ad<1.f)? 0.5f*d*d : ad-0.5f;
        d = bp2-t2; ad = fabsf(d); ssum += (ad<1.f)? 0.5f*d*d : ad-0.5f;
        d = bp3-t3; ad = fabsf(d); ssum += (ad<1.f)? 0.5f*d*d : ad-0.5f;
        cf = 1.f;
      }
      anp += wredf(cf);
      avb += wredf(bce);
      avc += wredf(ce);
      avl += wredf(ssum);
    }
    if (tid == 0) statG[c*BATCH + b] = make_float4(anp, avb, avc, avl);
  }

  if (c == 0 && b == 0 && tid < 4) out[tid] = 0.f;   // replaces memset dispatch

  // all threads: merge 4 wave-hists, plain coalesced store to private slab
  unsigned m0 = hist[tid] + hist[tid+256] + hist[tid+512] + hist[tid+768];
  slabG[((size_t)(c*BATCH + b))*NBUK + tid] = m0;
}

// Per-(s,b): merge chunk slabs + stats, top-k sum from histogram, final output.
// grid = 192 blocks x 256 threads, 1 bin/thread.
__global__ __launch_bounds__(256)
void select_kernel(const unsigned* __restrict__ slabG,
                   const float4* __restrict__ statG,
                   float* __restrict__ out)
{
  const int si = blockIdx.x;
  const int s = si >> 6, b = si & 63;
  const int t = threadIdx.x, lane = t & 63, w = t >> 6;
  __shared__ int   wtc[4];
  __shared__ float wts[4];
  __shared__ float sh_np, sh_vb, sh_vc, sh_vl;
  __shared__ int   sh_total;
  __shared__ float sh_negsum;

  // merge slabs (compile-time trip counts); unpack u32 (cnt<<21 | sum*2^8)
  int ci = 0; unsigned su = 0u;
  if (s == 0) {
    #pragma unroll
    for (int sl = 0; sl < 37; ++sl) {
      unsigned v = slabG[((size_t)((0+sl)*BATCH + b))*NBUK + t];
      ci += (int)(v >> 21); su += (v & MASK21);
    }
  } else if (s == 1) {
    #pragma unroll
    for (int sl = 0; sl < 10; ++sl) {
      unsigned v = slabG[((size_t)((37+sl)*BATCH + b))*NBUK + t];
      ci += (int)(v >> 21); su += (v & MASK21);
    }
  } else {
    #pragma unroll
    for (int sl = 0; sl < 3; ++sl) {
      unsigned v = slabG[((size_t)((47+sl)*BATCH + b))*NBUK + t];
      ci += (int)(v >> 21); su += (v & MASK21);
    }
  }
  const int   cnt = ci;
  const float sm  = (float)su * (1.f/256.f);

  // merge stats in wave 0
  if (w == 0) {
    const int cs = (s==0) ? 0 : ((s==1) ? 37 : 47);
    const int ns = (s==0) ? 37 : ((s==1) ? 10 : 3);
    float4 st = make_float4(0.f,0.f,0.f,0.f);
    if (lane < ns) st = statG[(cs+lane)*BATCH + b];
    st.x = wredf(st.x); st.y = wredf(st.y);
    st.z = wredf(st.z); st.w = wredf(st.w);
    if (lane == 0) { sh_np = st.x; sh_vb = st.y; sh_vc = st.z; sh_vl = st.w; }
  }

  // suffix scan: Cme = count in bins >= t
  int sc = cnt; float ss = sm;
  #pragma unroll
  for (int o = 1; o < 64; o <<= 1) {
    int   uc = __shfl_down(sc, o, 64);
    float us = __shfl_down(ss, o, 64);
    if (lane + o < 64) { sc += uc; ss += us; }
  }
  if (lane == 0) { wtc[w] = sc; wts[w] = ss; }
  __syncthreads();
  int wcs = 0; float wss = 0.f;
  #pragma unroll
  for (int ww = 0; ww < 4; ++ww) if (ww > w) { wcs += wtc[ww]; wss += wts[ww]; }
  const int   Cme = sc + wcs;
  const float Vme = ss + wss;
  if (t == 0) sh_total = Cme;
  __syncthreads();

  const int np = (int)sh_np;
  const int k = min(3*np, sh_total);
  const int   Cab = Cme - cnt;      // count strictly above this bin
  const float Vab = Vme - sm;
  if (k > 0 && Cme >= k && Cab < k) {  // unique boundary bin
    sh_negsum = Vab + (float)(k - Cab) * (sm / (float)cnt);
  }
  __syncthreads();
  if (t == 0) {
    float o = 0.f, cl = 0.f, lo = 0.f;
    if (np > 0) {
      float nf = (float)np;
      cl = sh_vc / nf;
      lo = sh_vl / (4.f * nf);
      if (k > 0) o = sh_vb / nf + sh_negsum / (float)k;
    }
    const float inv = 1.f / (float)BATCH;
    if (o  != 0.f) atomicAdd(&out[0], o  * inv);
    if (cl != 0.f) atomicAdd(&out[1], cl * inv);
    if (lo != 0.f) atomicAdd(&out[2], lo * inv);
    float tt = o + cl + lo;
    if (tt != 0.f) atomicAdd(&out[3], tt * inv);
  }
}

extern "C" void kernel_launch(void* const* d_in, const int* in_sizes, int n_in,
                              void* d_out, int out_size, void* d_ws, size_t ws_size,
                              hipStream_t stream)
{
  const float* p0 = (const float*)d_in[0];
  const float* p1 = (const float*)d_in[1];
  const float* p2 = (const float*)d_in[2];
  const float* tb = (const float*)d_in[6];
  const int*   tl = (const int*)d_in[7];
  float* out = (float*)d_out;

  unsigned* slabG = (unsigned*)d_ws;                    // 50*64*256 u32 = 3.28 MB
  float4* statG = (float4*)(slabG + (size_t)NCHUNK*BATCH*NBUK);

  score_kernel<<<dim3(NCHUNK, BATCH), 256, 0, stream>>>(p0, p1, p2,
      tb, tl, slabG, statG, out);

  select_kernel<<<NSTAT, 256, 0, stream>>>(slabG, statG, out);
}

// Round 17
// 38.714 us; speedup vs baseline: 1.3850x; 1.3850x over previous
//
#include <hip/hip_runtime.h>
#include <hip/hip_bf16.h>

#define BATCH 64
#define NGT 16
#define NSTAT 192
#define NBUK 256
#define NCHUNK 50
#define INV_IMG (1.0f/224.0f)
#define L2E 1.442695040888963f
#define LN2 0.693147180559945f
#define MASK21 ((1u<<21)-1u)

typedef float f32x2 __attribute__((ext_vector_type(2)));

__device__ __forceinline__ f32x2 v2max(f32x2 a, f32x2 b) { return __builtin_elementwise_max(a, b); }
__device__ __forceinline__ f32x2 v2min(f32x2 a, f32x2 b) { return __builtin_elementwise_min(a, b); }

__device__ __forceinline__ float wredf(float v) {
  #pragma unroll
  for (int o = 32; o > 0; o >>= 1) v += __shfl_down(v, o, 64);
  return v;
}
__device__ __forceinline__ float softplus_neg(float ax) {
  // log1p(exp(-ax)) for ax >= 0 via HW exp2/log2
  float e = __builtin_amdgcn_exp2f(-ax * L2E);
  return __builtin_amdgcn_logf(1.0f + e) * LN2;
}

// Per-anchor kernel: 4 anchors/thread within one row. Analytic anchors,
// y-hoist + block-uniform GT mask + wave ballot skip, packed-f32 IoU.
// Negatives -> per-WAVE u32 LDS hist (cnt<<21 | sum*2^8).
// Positives -> tiny LDS queue; processed post-barrier by wave 0 lane-parallel.
// grid = (50 chunks, BATCH).  [R11 verified best: 39.5 us total]
__global__ __launch_bounds__(256, 6)
void score_kernel(const float* __restrict__ p0, const float* __restrict__ p1,
                  const float* __restrict__ p2,
                  const float* __restrict__ tboxes, const int* __restrict__ tlabels,
                  unsigned* __restrict__ slabG,
                  float4* __restrict__ statG, float* __restrict__ out)
{
  const int c = blockIdx.x, b = blockIdx.y;
  const int tid = threadIdx.x;
  const int wv = tid >> 6;

  int s, ch, row, x0, W, HH; float st, sh; const float* pred; bool valid;
  if (c < 37) {
    int seg = c*256 + tid; valid = seg < 9408;
    if (!valid) seg = 0;
    ch = seg / 3136; int rem = seg - ch*3136; row = rem / 28; x0 = (rem - row*28)*4;
    s=0; W=112; HH=12544; st=2.f; sh=8.f+4.f*(float)ch; pred=p0;
  } else if (c < 47) {
    int seg = (c-37)*256 + tid; valid = seg < 2352;
    if (!valid) seg = 0;
    ch = seg / 784; int rem = seg - ch*784; row = rem / 14; x0 = (rem - row*14)*4;
    s=1; W=56; HH=3136; st=4.f; sh=24.f+8.f*(float)ch; pred=p1;
  } else {
    int seg = (c-47)*256 + tid; valid = seg < 588;
    if (!valid) seg = 0;
    ch = seg / 196; int rem = seg - ch*196; row = rem / 7; x0 = (rem - row*7)*4;
    s=2; W=28; HH=784; st=8.f; sh=48.f+16.f*(float)ch; pred=p2;
  }

  if (c == 0 && b == 0 && tid < 4) out[tid] = 0.f;   // replaces memset dispatch

  __shared__ float sbx1[NGT], sby1[NGT], sbx2[NGT], sby2[NGT], sab[NGT];
  __shared__ unsigned hist[4*NBUK];    // per-wave private, u32 packed
  __shared__ int sqcnt;
  __shared__ unsigned squeue[1024];
  __shared__ unsigned smask;

  #pragma unroll
  for (int j = 0; j < 4; ++j) hist[tid + 256*j] = 0u;
  if (tid == 0) sqcnt = 0;
  bool keep = false;
  if (tid < NGT) {
    float x1 = tboxes[(b*NGT + tid)*4 + 0] * INV_IMG;
    float y1 = tboxes[(b*NGT + tid)*4 + 1] * INV_IMG;
    float x2 = tboxes[(b*NGT + tid)*4 + 2] * INV_IMG;
    float y2 = tboxes[(b*NGT + tid)*4 + 3] * INV_IMG;
    sbx1[tid]=x1; sby1[tid]=y1; sbx2[tid]=x2; sby2[tid]=y2;
    sab[tid] = (x2-x1)*(y2-y1);
    // block y-band (uniform): rows of segLo..segHi, conservative max half-size
    int base, lim, per, wseg;
    if (s == 0)      { base = c*256;      lim = 9408; per = 3136; wseg = 28; }
    else if (s == 1) { base = (c-37)*256; lim = 2352; per = 784;  wseg = 14; }
    else             { base = (c-47)*256; lim = 588;  per = 196;  wseg = 7;  }
    int segLo = base, segHi = min(base + 255, lim - 1);
    int chLo = segLo / per, chHi = segHi / per;
    int rLo = (segLo - chLo*per) / wseg, rHi = (segHi - chHi*per) / wseg;
    if (chLo != chHi) { rLo = 0; rHi = W - 1; }
    float shm = (s==0) ? 16.f : ((s==1) ? 40.f : 80.f);
    float by1 = (((float)rLo + 0.5f)*st - shm) * INV_IMG;
    float by2 = (((float)rHi + 0.5f)*st + shm) * INV_IMG;
    keep = (y2 >= by1) && (y1 <= by2);
  }
  unsigned mk = (unsigned)(__ballot(keep) & 0xFFFFULL);
  if (tid == 0) smask = mk;
  __syncthreads();
  const unsigned mask = smask;

  // analytic anchors (bit-identical to reference values)
  const float fy  = ((float)row + 0.5f)*st;
  const float ay1 = (fy - sh)*INV_IMG;
  const float ay2 = (fy + sh)*INV_IMG;
  const float A0  = ((float)x0 + 0.5f)*st - sh;
  const float hA  = ay2 - ay1;
  f32x2 ax1a, ax1b, ax2a, ax2b;
  {
    float f0 = A0, f1 = A0 + st, f2 = A0 + st*2.f, f3 = A0 + st*3.f;
    ax1a = (f32x2){f0*INV_IMG, f1*INV_IMG};
    ax1b = (f32x2){f2*INV_IMG, f3*INV_IMG};
    ax2a = (f32x2){(f0+2.f*sh)*INV_IMG, (f1+2.f*sh)*INV_IMG};
    ax2b = (f32x2){(f2+2.f*sh)*INV_IMG, (f3+2.f*sh)*INV_IMG};
  }
  const f32x2 hAv = (f32x2){hA, hA};
  const f32x2 arA = (ax2a - ax1a) * hAv;
  const f32x2 arB = (ax2b - ax1b) * hAv;
  f32x2 bIa = (f32x2){-1.f,-1.f}, bIb = (f32x2){-1.f,-1.f};
  f32x2 bDa = (f32x2){1.f,1.f},   bDb = (f32x2){1.f,1.f};
  int bj0 = 0, bj1 = 0, bj2 = 0, bj3 = 0;

  const int hw0 = row*W + x0;
  const float* pb = pred + ((size_t)b*24 + (size_t)ch*8) * (size_t)HH;
  float4 o0 = make_float4(0.f,0.f,0.f,0.f);
  if (valid) o0 = *reinterpret_cast<const float4*>(pb + 4*HH + hw0);
  float obj[4] = {o0.x,o0.y,o0.z,o0.w};

  const f32x2 zero2 = (f32x2){0.f, 0.f};
  const f32x2 eps2  = (f32x2){1e-9f, 1e-9f};
  #pragma unroll
  for (int j = 0; j < NGT; ++j) {
    if (!(mask & (1u << j))) continue;          // block-uniform cheap skip
    float ly = fmaxf(ay1, sby1[j]);
    float ry = fminf(ay2, sby2[j]);
    float hy = ry - ly;
    if (__ballot(hy > 0.f)) {
      float h = fmaxf(hy, 0.f);
      float bx1 = sbx1[j], bx2 = sbx2[j], ab = sab[j];
      const f32x2 hv  = (f32x2){h, h};
      const f32x2 b1v = (f32x2){bx1, bx1};
      const f32x2 b2v = (f32x2){bx2, bx2};
      const f32x2 abv = (f32x2){ab, ab};
      // pair A (q=0,1): identical FP order to scalar version
      f32x2 wA = v2max(v2min(ax2a, b2v) - v2max(ax1a, b1v), zero2);
      f32x2 iA = wA * hv;
      f32x2 dA = (arA + abv) - iA + eps2;
      f32x2 lA = iA * bDa, rA = bIa * dA;
      bool u0 = lA.x > rA.x, u1 = lA.y > rA.y;
      bIa.x = u0 ? iA.x : bIa.x;  bDa.x = u0 ? dA.x : bDa.x;  bj0 = u0 ? j : bj0;
      bIa.y = u1 ? iA.y : bIa.y;  bDa.y = u1 ? dA.y : bDa.y;  bj1 = u1 ? j : bj1;
      // pair B (q=2,3)
      f32x2 wB = v2max(v2min(ax2b, b2v) - v2max(ax1b, b1v), zero2);
      f32x2 iB = wB * hv;
      f32x2 dB = (arB + abv) - iB + eps2;
      f32x2 lB = iB * bDb, rB = bIb * dB;
      bool u2 = lB.x > rB.x, u3 = lB.y > rB.y;
      bIb.x = u2 ? iB.x : bIb.x;  bDb.x = u2 ? dB.x : bDb.x;  bj2 = u2 ? j : bj2;
      bIb.y = u3 ? iB.y : bIb.y;  bDb.y = u3 ? dB.y : bDb.y;  bj3 = u3 ? j : bj3;
    }
  }

  const float bIq[4] = {bIa.x, bIa.y, bIb.x, bIb.y};
  const float bDq[4] = {bDa.x, bDa.y, bDb.x, bDb.y};
  const int   bjq[4] = {bj0, bj1, bj2, bj3};

  unsigned* myhist = hist + wv*NBUK;
  #pragma unroll
  for (int q = 0; q < 4; ++q) {
    bool pos = valid && (bIq[q] >= 0.5f*bDq[q]);   // iou >= 0.5 (div-free)
    bool neg = valid && (bIq[q] <  0.4f*bDq[q]);   // iou <  0.4
    if (neg) {
      float x = obj[q];
      float bce = fmaxf(x, 0.f) + softplus_neg(fabsf(x));
      int bk = min(NBUK-1, (int)(bce * 32.f));
      unsigned pk = (1u << 21) | (unsigned)(bce * 256.f + 0.5f);
      atomicAdd(&myhist[bk], pk);
    }
    if (pos) {     // rare: defer everything to wave-0 phase
      int qi = atomicAdd(&sqcnt, 1);
      squeue[qi] = ((unsigned)ch<<18) | ((unsigned)bjq[q]<<14)
                 | ((unsigned)row<<7) | (unsigned)(x0 + q);
    }
  }
  __syncthreads();

  // wave 0: process queued positives lane-parallel (loads overlap across lanes)
  if (tid < 64) {
    const int n = sqcnt;
    float anp = 0.f, avb = 0.f, avc = 0.f, avl = 0.f;
    for (int base = 0; base < n; base += 64) {
      int i = base + tid;
      float cf = 0.f, bce = 0.f, ce = 0.f, ssum = 0.f;
      if (i < n) {
        unsigned rec = squeue[i];
        int x   = rec & 127;
        int rw  = (rec >> 7) & 127;
        int j   = (rec >> 14) & 15;
        int ch2 = (rec >> 18) & 3;
        float sh2 = (s==0) ? 8.f+4.f*(float)ch2
                  : (s==1) ? 24.f+8.f*(float)ch2 : 48.f+16.f*(float)ch2;
        const float* pbq = pred + ((size_t)b*24 + (size_t)ch2*8) * (size_t)HH;
        const int hw = rw*W + x;
        // anchor (bit-identical analytic form)
        float fyq = ((float)rw + 0.5f)*st;
        float qay1 = (fyq - sh2)*INV_IMG, qay2 = (fyq + sh2)*INV_IMG;
        float fx = ((float)x + 0.5f)*st - sh2;
        float qax1 = fx*INV_IMG, qax2 = (fx + 2.f*sh2)*INV_IMG;

        float xo = pbq[4*HH + hw];
        bce = fmaxf(xo, 0.f) - xo + softplus_neg(fabsf(xo));

        float c0 = pbq[5*HH + hw], c1 = pbq[6*HH + hw], c2 = pbq[7*HH + hw];
        float m = fmaxf(c0, fmaxf(c1, c2));
        float e0 = __builtin_amdgcn_exp2f((c0-m)*L2E);
        float e1 = __builtin_amdgcn_exp2f((c1-m)*L2E);
        float e2 = __builtin_amdgcn_exp2f((c2-m)*L2E);
        float lse = m + __builtin_amdgcn_logf(e0+e1+e2) * LN2;
        int lab = tlabels[b*NGT + j] - 1;
        float cl = (lab==0)?c0:((lab==1)?c1:c2);
        ce = lse - cl;

        float bx1=sbx1[j], by1=sby1[j], bx2=sbx2[j], by2=sby2[j];
        float gcx = 0.5f*(bx1+bx2), gcy = 0.5f*(by1+by2);
        float gw = bx2-bx1, gh = by2-by1;
        float acx = 0.5f*(qax1+qax2), acy = 0.5f*(qay1+qay2);
        float aw = qax2-qax1, ah = qay2-qay1;
        float t0 = (gcx-acx)/aw;
        float t1 = (gcy-acy)/ah;
        float t2 = __builtin_amdgcn_logf(gw/aw + 1e-6f) * LN2;
        float t3 = __builtin_amdgcn_logf(gh/ah + 1e-6f) * LN2;
        float bp0 = pbq[0*HH+hw], bp1 = pbq[1*HH+hw];
        float bp2 = pbq[2*HH+hw], bp3 = pbq[3*HH+hw];
        float d, ad;
        d = bp0-t0; ad = fabsf(d); ssum += (ad<1.f)? 0.5f*d*d : ad-0.5f;
        d = bp1-t1; ad = fabsf(d); ssum += (ad<1.f)? 0.5f*d*d : ad-0.5f;
        d = bp2-t2; ad = fabsf(d); ssum += (ad<1.f)? 0.5f*d*d : ad-0.5f;
        d = bp3-t3; ad = fabsf(d); ssum += (ad<1.f)? 0.5f*d*d : ad-0.5f;
        cf = 1.f;
      }
      anp += wredf(cf);
      avb += wredf(bce);
      avc += wredf(ce);
      avl += wredf(ssum);
    }
    if (tid == 0) statG[c*BATCH + b] = make_float4(anp, avb, avc, avl);
  }

  // all threads: merge 4 wave-hists, plain coalesced store to private slab
  unsigned m0 = hist[tid] + hist[tid+256] + hist[tid+512] + hist[tid+768];
  slabG[((size_t)(c*BATCH + b))*NBUK + tid] = m0;
}

// Per-(s,b): merge chunk slabs + stats, top-k sum from histogram, final output.
// grid = 192 blocks x 256 threads, 1 bin/thread.
__global__ __launch_bounds__(256)
void select_kernel(const unsigned* __restrict__ slabG,
                   const float4* __restrict__ statG,
                   float* __restrict__ out)
{
  const int si = blockIdx.x;
  const int s = si >> 6, b = si & 63;
  const int t = threadIdx.x, lane = t & 63, w = t >> 6;
  __shared__ int   wtc[4];
  __shared__ float wts[4];
  __shared__ float sh_np, sh_vb, sh_vc, sh_vl;
  __shared__ int   sh_total;
  __shared__ float sh_negsum;

  // merge slabs (compile-time trip counts); unpack u32 (cnt<<21 | sum*2^8)
  int ci = 0; unsigned su = 0u;
  if (s == 0) {
    #pragma unroll
    for (int sl = 0; sl < 37; ++sl) {
      unsigned v = slabG[((size_t)((0+sl)*BATCH + b))*NBUK + t];
      ci += (int)(v >> 21); su += (v & MASK21);
    }
  } else if (s == 1) {
    #pragma unroll
    for (int sl = 0; sl < 10; ++sl) {
      unsigned v = slabG[((size_t)((37+sl)*BATCH + b))*NBUK + t];
      ci += (int)(v >> 21); su += (v & MASK21);
    }
  } else {
    #pragma unroll
    for (int sl = 0; sl < 3; ++sl) {
      unsigned v = slabG[((size_t)((47+sl)*BATCH + b))*NBUK + t];
      ci += (int)(v >> 21); su += (v & MASK21);
    }
  }
  const int   cnt = ci;
  const float sm  = (float)su * (1.f/256.f);

  // merge stats in wave 0
  if (w == 0) {
    const int cs = (s==0) ? 0 : ((s==1) ? 37 : 47);
    const int ns = (s==0) ? 37 : ((s==1) ? 10 : 3);
    float4 st = make_float4(0.f,0.f,0.f,0.f);
    if (lane < ns) st = statG[(cs+lane)*BATCH + b];
    st.x = wredf(st.x); st.y = wredf(st.y);
    st.z = wredf(st.z); st.w = wredf(st.w);
    if (lane == 0) { sh_np = st.x; sh_vb = st.y; sh_vc = st.z; sh_vl = st.w; }
  }

  // suffix scan: Cme = count in bins >= t
  int sc = cnt; float ss = sm;
  #pragma unroll
  for (int o = 1; o < 64; o <<= 1) {
    int   uc = __shfl_down(sc, o, 64);
    float us = __shfl_down(ss, o, 64);
    if (lane + o < 64) { sc += uc; ss += us; }
  }
  if (lane == 0) { wtc[w] = sc; wts[w] = ss; }
  __syncthreads();
  int wcs = 0; float wss = 0.f;
  #pragma unroll
  for (int ww = 0; ww < 4; ++ww) if (ww > w) { wcs += wtc[ww]; wss += wts[ww]; }
  const int   Cme = sc + wcs;
  const float Vme = ss + wss;
  if (t == 0) sh_total = Cme;
  __syncthreads();

  const int np = (int)sh_np;
  const int k = min(3*np, sh_total);
  const int   Cab = Cme - cnt;      // count strictly above this bin
  const float Vab = Vme - sm;
  if (k > 0 && Cme >= k && Cab < k) {  // unique boundary bin
    sh_negsum = Vab + (float)(k - Cab) * (sm / (float)cnt);
  }
  __syncthreads();
  if (t == 0) {
    float o = 0.f, cl = 0.f, lo = 0.f;
    if (np > 0) {
      float nf = (float)np;
      cl = sh_vc / nf;
      lo = sh_vl / (4.f * nf);
      if (k > 0) o = sh_vb / nf + sh_negsum / (float)k;
    }
    const float inv = 1.f / (float)BATCH;
    if (o  != 0.f) atomicAdd(&out[0], o  * inv);
    if (cl != 0.f) atomicAdd(&out[1], cl * inv);
    if (lo != 0.f) atomicAdd(&out[2], lo * inv);
    float tt = o + cl + lo;
    if (tt != 0.f) atomicAdd(&out[3], tt * inv);
  }
}

extern "C" void kernel_launch(void* const* d_in, const int* in_sizes, int n_in,
                              void* d_out, int out_size, void* d_ws, size_t ws_size,
                              hipStream_t stream)
{
  const float* p0 = (const float*)d_in[0];
  const float* p1 = (const float*)d_in[1];
  const float* p2 = (const float*)d_in[2];
  const float* tb = (const float*)d_in[6];
  const int*   tl = (const int*)d_in[7];
  float* out = (float*)d_out;

  unsigned* slabG = (unsigned*)d_ws;                    // 50*64*256 u32 = 3.28 MB
  float4* statG = (float4*)(slabG + (size_t)NCHUNK*BATCH*NBUK);

  score_kernel<<<dim3(NCHUNK, BATCH), 256, 0, stream>>>(p0, p1, p2,
      tb, tl, slabG, statG, out);

  select_kernel<<<NSTAT, 256, 0, stream>>>(slabG, statG, out);
}